// Round 14
// baseline (1467.469 us; speedup 1.0000x reference)
//
#include <hip/hip_runtime.h>
#include <hip/hip_bf16.h>

// Problem constants (fixed by reference)
#define SEQ 784
#define BS  256
#define DH  512
#define MT  (SEQ * BS)   // 200704 rows
#define NL  3
#define NC  14           // scan chunks
#define CL  56           // chunk length (NC*CL == SEQ)
#define COLS (BS * DH)   // 131072 = 2^17

typedef unsigned short u16;
typedef __bf16  bf16x8  __attribute__((ext_vector_type(8)));
typedef float   f32x4   __attribute__((ext_vector_type(4)));
typedef unsigned short u16x8 __attribute__((ext_vector_type(8)));
typedef unsigned short u16x4 __attribute__((ext_vector_type(4)));
// (not ushortN: HIP's amd_hip_vector_types.h owns those names — R8 failure)

__device__ __forceinline__ u16 f2b(float f) {
    unsigned int x = __float_as_uint(f);
    unsigned int r = (x + 0x7FFFu + ((x >> 16) & 1u)) >> 16;   // RNE
    return (u16)r;
}
__device__ __forceinline__ float b2f(u16 u) {
    return __uint_as_float(((unsigned int)u) << 16);
}

// ---------------------------------------------------------------------------
// prep: pack B[l],C[l] (f32 (l,k,n)) -> bf16 MFMA-fragment order:
//   n = wd*64 + ni*16 + (lane&15);  k = g*32 + (lane>>4)*8 + e
// ---------------------------------------------------------------------------
__global__ __launch_bounds__(256) void prep_k(const float* __restrict__ B,
                                              const float* __restrict__ C,
                                              u16* __restrict__ Bp,
                                              u16* __restrict__ Cp)
{
    const long t = (long)blockIdx.x * 256 + threadIdx.x;   // 0 .. 3*2^18-1
    const int  e  = (int)(t & 7);
    const int  l  = (int)((t >> 3) & 63);
    const int  ni = (int)((t >> 9) & 3);
    const int  wd = (int)((t >> 11) & 7);
    const int  g  = (int)((t >> 14) & 15);
    const long lay = t >> 18;
    const int  n = wd * 64 + ni * 16 + (l & 15);
    const int  k = g * 32 + (l >> 4) * 8 + e;
    const long src = (lay << 18) + (long)k * DH + n;
    Bp[t] = f2b(B[src]);
    Cp[t] = f2b(C[src]);
}

// ===========================================================================
// GEMM family — measured-best core (R7/R12: ~120us, m97-ceiling-bound):
// 64x512 tile, 512 threads = 8 waves (wid = 64-col N-block),
// mfma_f32_16x16x32_bf16; W fragment-packed from L2 (coalesced dwordx4);
// A 64x64 sub-tile double-buffered in LDS, source-side XOR swizzle
// (conflict-free). Plain __syncthreads only.
//
// gemm_dual (R13/R14): fuses boundary GEMM2(l)+GEMM1(l+1); Y = relu(hs@C)
// lives only in LDS (A-staging swizzle format). R14 FIX: ONE accumulator
// array reused for both K-loops — R13's two live acc arrays blew the
// 128-VGPR cap from __launch_bounds__(512,4) and spilled ~470B/thread
// (FETCH 516MB / WRITE 959MB of scratch traffic, dur 498us).
// ===========================================================================

#define GEMM_STEP_KK(ATILE, tt, ACC, WP)                                         \
    _Pragma("unroll")                                                            \
    for (int kk = 0; kk < 2; ++kk) {                                             \
        bf16x8 bv[4];                                                            \
        _Pragma("unroll")                                                        \
        for (int ni = 0; ni < 4; ++ni)                                           \
            bv[ni] = *(const bf16x8*)&(WP)[((long)((2 * (tt) + kk) * 32 +        \
                                                   wid * 4 + ni) << 9) +         \
                                           (lane << 3)];                         \
        const int fcol = ((kk * 4 + (lane >> 4)) ^ (lane & 7)) * 8;              \
        bf16x8 af[4];                                                            \
        _Pragma("unroll")                                                        \
        for (int i = 0; i < 4; ++i)                                              \
            af[i] = *(const bf16x8*)&(ATILE)[(i * 16 + (lane & 15)) * 64 + fcol];\
        _Pragma("unroll")                                                        \
        for (int mi = 0; mi < 4; ++mi)                                           \
            _Pragma("unroll")                                                    \
            for (int ni = 0; ni < 4; ++ni)                                       \
                (ACC)[mi][ni] = __builtin_amdgcn_mfma_f32_16x16x32_bf16(         \
                    af[mi], bv[ni], (ACC)[mi][ni], 0, 0, 0);                     \
    }

// Staged K-loop (prologue stage + per-step dbuf stage + __syncthreads)
#define GEMM_STAGED_KLOOP(ACC, WP)                                              \
    __builtin_amdgcn_global_load_lds(                                           \
        (const __attribute__((address_space(1))) void*)gax,                     \
        (__attribute__((address_space(3))) void*)                               \
            ((__attribute__((address_space(3))) char*)lds + tid * 16),          \
        16, 0, 0);                                                              \
    for (int t = 0; t < 8; ++t) {                                               \
        __syncthreads();                                                        \
        if (t < 7) {                                                            \
            __builtin_amdgcn_global_load_lds(                                   \
                (const __attribute__((address_space(1))) void*)(gax + (t + 1) * 64), \
                (__attribute__((address_space(3))) void*)                       \
                    ((__attribute__((address_space(3))) char*)lds +             \
                     ((t + 1) & 1) * 8192 + tid * 16),                          \
                16, 0, 0);                                                      \
        }                                                                       \
        const u16* Atile = lds + (t & 1) * 4096;                                \
        GEMM_STEP_KK(Atile, t, ACC, WP)                                         \
    }                                                                           \
    __syncthreads();

// Standard C-tile epilogue (LDS-staged coalesced stores, row-group swizzle)
#define GEMM_C_EPILOGUE(CT, ACC, RELU_FLAG, DST)                                \
    {                                                                           \
        const int rbase = (lane >> 4) * 4;                                      \
        const int cloc  = wid * 64 + (lane & 15);                               \
        _Pragma("unroll")                                                       \
        for (int mi = 0; mi < 4; ++mi)                                          \
            _Pragma("unroll")                                                   \
            for (int ni = 0; ni < 4; ++ni)                                      \
                _Pragma("unroll")                                               \
                for (int r = 0; r < 4; ++r) {                                   \
                    float v = (ACC)[mi][ni][r];                                 \
                    if (RELU_FLAG) v = fmaxf(v, 0.f);                           \
                    const int row = mi * 16 + rbase + r;                        \
                    const int col = (cloc + ni * 16) ^ (((row >> 2) & 3) * 16); \
                    (CT)[row * 512 + col] = f2b(v);                             \
                }                                                               \
        __syncthreads();                                                        \
        _Pragma("unroll")                                                       \
        for (int p = 0; p < 8; ++p) {                                           \
            const int e   = p * 4096 + tid * 8;                                 \
            const int row = e >> 9;                                             \
            const int col = e & 511;                                            \
            const int csw = col ^ (((row >> 2) & 3) * 16);                      \
            *(u16x8*)&(DST)[(bm + row) * DH + col] =                            \
                *(const u16x8*)&(CT)[row * 512 + csw];                          \
        }                                                                       \
    }

// ---- layer-0 GEMM1 with fused h0: A panel COMPUTED in-LDS from x,W0,b0 ----
__global__ __launch_bounds__(512, 4) void gemm_first(const float* __restrict__ x,
                                                     const float* __restrict__ W0,
                                                     const float* __restrict__ b0,
                                                     const u16* __restrict__ Wp,
                                                     u16* __restrict__ Y)
{
    __shared__ __align__(16) u16 lds[64 * 512];   // full A panel, aliased C tile

    const int tid  = threadIdx.x;
    const int lane = tid & 63;
    const int wid  = tid >> 6;
    const long bm  = (long)blockIdx.x * 64;

    const int prow = tid >> 3;
    const int slot = tid & 7;
    const float xv = x[bm + prow];

#pragma unroll
    for (int t = 0; t < 8; ++t) {
        const int k0 = t * 64 + ((slot ^ (prow & 7)) * 8);
        u16x8 o;
#pragma unroll
        for (int e = 0; e < 8; ++e)
            o[e] = f2b(fmaxf(fmaf(xv, W0[k0 + e], b0[k0 + e]), 0.f));
        *(u16x8*)&lds[t * 4096 + tid * 8] = o;
    }

    f32x4 acc[4][4];
#pragma unroll
    for (int i = 0; i < 4; ++i)
#pragma unroll
        for (int j = 0; j < 4; ++j)
            acc[i][j] = (f32x4){0.f, 0.f, 0.f, 0.f};

    __syncthreads();

#pragma unroll
    for (int t = 0; t < 8; ++t) {
        const u16* Atile = lds + t * 4096;
        GEMM_STEP_KK(Atile, t, acc, Wp)
    }
    __syncthreads();

    u16* Ctile = lds;
    GEMM_C_EPILOGUE(Ctile, acc, 0, Y)
}

// ---- fused boundary: xb_{l+1} = relu(hs @ C_l) @ B_{l+1} -------------------
// K-loop-1 (staged from buf) -> Y into LDS in A-staging swizzle format
// -> re-zero THE SAME acc -> K-loop-2 (A from LDS) -> epilogue to buf.
// LDS: A-dbuf 16KB @0 + Y 64KB = 80KB -> 2 blocks/CU. Peak VGPR = gemm_ip's.
__global__ __launch_bounds__(512, 4) void gemm_dual(const u16* __restrict__ X,
                                                    const u16* __restrict__ WpC,
                                                    const u16* __restrict__ WpB,
                                                    u16* __restrict__ Yout)
{
    __shared__ __align__(16) u16 lds[8192 + 8 * 4096];   // 80 KB

    const int tid  = threadIdx.x;
    const int lane = tid & 63;
    const int wid  = tid >> 6;
    const long bm  = (long)blockIdx.x * 64;

    const int srow = tid >> 3;
    const int scol = (((tid & 7) ^ (srow & 7)) * 8);
    const u16* gax = X + (bm + srow) * DH + scol;

    f32x4 acc[4][4];
#pragma unroll
    for (int i = 0; i < 4; ++i)
#pragma unroll
        for (int j = 0; j < 4; ++j)
            acc[i][j] = (f32x4){0.f, 0.f, 0.f, 0.f};

    // ---- K-loop 1: T = hs @ C  (staged A from global) ----
    GEMM_STAGED_KLOOP(acc, WpC)

    // ---- write Y = relu(T) into LDS, A-staging swizzle format ----
    // logical (row, col): t = col>>6 == wid (each wave owns its own tile),
    // chunk = (col&63)>>3, e = col&7; dest chunk is XOR'd with row&7.
    u16* Yr = lds + 8192;
    {
        const int rbase = (lane >> 4) * 4;
#pragma unroll
        for (int mi = 0; mi < 4; ++mi)
#pragma unroll
            for (int ni = 0; ni < 4; ++ni) {
                const int chunk = ni * 2 + ((lane & 15) >> 3);
#pragma unroll
                for (int r = 0; r < 4; ++r) {
                    const int row = mi * 16 + rbase + r;
                    Yr[wid * 4096 + row * 64 + ((chunk ^ (row & 7)) * 8) + (lane & 7)]
                        = f2b(fmaxf(acc[mi][ni][r], 0.f));
                }
            }
    }
    __syncthreads();

    // ---- K-loop 2: xb = Y @ B — REUSE acc (R14 spill fix) ----
#pragma unroll
    for (int i = 0; i < 4; ++i)
#pragma unroll
        for (int j = 0; j < 4; ++j)
            acc[i][j] = (f32x4){0.f, 0.f, 0.f, 0.f};

#pragma unroll
    for (int t = 0; t < 8; ++t) {
        const u16* Atile = Yr + t * 4096;
        GEMM_STEP_KK(Atile, t, acc, WpB)
    }
    __syncthreads();   // done reading Y; reuse Yr as C tile

    u16* Ctile = Yr;
    GEMM_C_EPILOGUE(Ctile, acc, 0, Yout)
}

// ---- layer-2 GEMM2 with fused final: out = relu(X@C)@Wf + bf + x ----------
__global__ __launch_bounds__(512, 4) void gemm_last(const u16* __restrict__ X,
                                                    const u16* __restrict__ Wp,
                                                    const float* __restrict__ Wf,
                                                    const float* __restrict__ bf_,
                                                    const float* __restrict__ x,
                                                    float* __restrict__ out)
{
    __shared__ __align__(16) u16 lds[64 * 512];
    float* partials = (float*)lds;             // [8][64] f32, used after K-loop

    const int tid  = threadIdx.x;
    const int lane = tid & 63;
    const int wid  = tid >> 6;
    const long bm  = (long)blockIdx.x * 64;

    const int srow = tid >> 3;
    const int scol = (((tid & 7) ^ (srow & 7)) * 8);
    const u16* gax = X + (bm + srow) * DH + scol;

    f32x4 acc[4][4];
#pragma unroll
    for (int i = 0; i < 4; ++i)
#pragma unroll
        for (int j = 0; j < 4; ++j)
            acc[i][j] = (f32x4){0.f, 0.f, 0.f, 0.f};

    GEMM_STAGED_KLOOP(acc, Wp)   // ends with __syncthreads(); lds -> partials

    const int cbase = wid * 64 + (lane & 15);
    float wf[4];
#pragma unroll
    for (int ni = 0; ni < 4; ++ni) wf[ni] = Wf[cbase + ni * 16];

    float part[4][4];
#pragma unroll
    for (int mi = 0; mi < 4; ++mi)
#pragma unroll
        for (int r = 0; r < 4; ++r) {
            float s = 0.f;
#pragma unroll
            for (int ni = 0; ni < 4; ++ni)
                s = fmaf(fmaxf(acc[mi][ni][r], 0.f), wf[ni], s);
            part[mi][r] = s;
        }
#pragma unroll
    for (int mi = 0; mi < 4; ++mi)
#pragma unroll
        for (int r = 0; r < 4; ++r) {
#pragma unroll
            for (int off = 1; off < 16; off <<= 1)
                part[mi][r] += __shfl_xor(part[mi][r], off, 64);
        }
    if ((lane & 15) == 0) {
        const int q = lane >> 4;
#pragma unroll
        for (int mi = 0; mi < 4; ++mi)
#pragma unroll
            for (int r = 0; r < 4; ++r)
                partials[wid * 64 + mi * 16 + q * 4 + r] = part[mi][r];
    }
    __syncthreads();
    if (tid < 64) {
        float s = 0.f;
#pragma unroll
        for (int w = 0; w < 8; ++w) s += partials[w * 64 + tid];
        out[bm + tid] = s + bf_[0] + x[bm + tid];
    }
}

// ---------------------------------------------------------------------------
// Chunked parallel scan, 2 phases (scanB fused into scanC's prologue —
// verified absmax-identical). u16x4 vectorized (4 cols/thread).
// ---------------------------------------------------------------------------
__global__ __launch_bounds__(256) void scanA_k(const u16* __restrict__ buf,
                                               const float* __restrict__ a_all,
                                               int layer,
                                               float* __restrict__ carry)
{
    const long T   = (long)blockIdx.x * 256 + threadIdx.x;  // 0 .. NC*COLS/4-1
    const int col4 = (int)(T & (COLS / 4 - 1)) * 4;
    const int c    = (int)(T >> 15);
    const f32x4 av = *(const f32x4*)&a_all[layer * DH + (col4 & (DH - 1))];
    const u16* p = buf + (long)c * CL * COLS + col4;

    float h[4] = {0.f, 0.f, 0.f, 0.f};
    u16x4 pre[8];
#pragma unroll
    for (int i = 0; i < 8; ++i) pre[i] = *(const u16x4*)&p[(long)i * COLS];
    for (int s8 = 0; s8 < CL; s8 += 8) {
        const bool more = (s8 + 8) < CL;
#pragma unroll
        for (int j = 0; j < 8; ++j) {
            const u16x4 v = pre[j];
            if (more) pre[j] = *(const u16x4*)&p[(long)(s8 + 8 + j) * COLS];
#pragma unroll
            for (int i = 0; i < 4; ++i)
                h[i] = fmaf(h[i], av[i], b2f((u16)v[i]));
        }
    }
    *(f32x4*)&carry[(long)c * COLS + col4] = (f32x4){h[0], h[1], h[2], h[3]};
}

// Phase C (+fused B): carry-in = prefix of raw carries (c uniform per block;
// identical fp recurrence to the old scanB); then scan CL steps, write bf16.
__global__ __launch_bounds__(256) void scanC_k(u16* __restrict__ buf,
                                               const float* __restrict__ a_all,
                                               int layer,
                                               const float* __restrict__ carry)
{
    const long T   = (long)blockIdx.x * 256 + threadIdx.x;
    const int col4 = (int)(T & (COLS / 4 - 1)) * 4;
    const int c    = (int)(T >> 15);
    const f32x4 av = *(const f32x4*)&a_all[layer * DH + (col4 & (DH - 1))];
    u16* p = buf + (long)c * CL * COLS + col4;

    float h[4];
#pragma unroll
    for (int i = 0; i < 4; ++i) h[i] = 0.f;
    {
        float pw[4];
#pragma unroll
        for (int i = 0; i < 4; ++i) {
            float a2 = av[i] * av[i], a4 = a2 * a2, a8 = a4 * a4;
            float a16 = a8 * a8, a32 = a16 * a16;
            pw[i] = a32 * a16 * a8;            // a^56
        }
        for (int cc = 0; cc < c; ++cc) {       // c uniform within block
            const f32x4 cr = *(const f32x4*)&carry[(long)cc * COLS + col4];
#pragma unroll
            for (int i = 0; i < 4; ++i)
                h[i] = fmaf(h[i], pw[i], cr[i]);
        }
    }

    u16x4 pre[8];
#pragma unroll
    for (int i = 0; i < 8; ++i) pre[i] = *(const u16x4*)&p[(long)i * COLS];
    for (int s8 = 0; s8 < CL; s8 += 8) {
        const bool more = (s8 + 8) < CL;
#pragma unroll
        for (int j = 0; j < 8; ++j) {
            const u16x4 v = pre[j];
            if (more) pre[j] = *(const u16x4*)&p[(long)(s8 + 8 + j) * COLS];
            u16x4 o;
#pragma unroll
            for (int i = 0; i < 4; ++i) {
                h[i] = fmaf(h[i], av[i], b2f((u16)v[i]));
                o[i] = f2b(h[i]);
            }
            *(u16x4*)&p[(long)(s8 + j) * COLS] = o;
        }
    }
}

// ---------------------------------------------------------------------------
extern "C" void kernel_launch(void* const* d_in, const int* in_sizes, int n_in,
                              void* d_out, int out_size, void* d_ws, size_t ws_size,
                              hipStream_t stream)
{
    const float* x   = (const float*)d_in[0];
    const float* W0  = (const float*)d_in[1];
    const float* b0  = (const float*)d_in[2];
    const float* a   = (const float*)d_in[3];
    const float* B   = (const float*)d_in[4];
    const float* C   = (const float*)d_in[5];
    const float* Wf  = (const float*)d_in[6];
    const float* bf_ = (const float*)d_in[7];
    float* out = (float*)d_out;

    const long BUF = (long)MT * DH;                  // 102,760,448 elements (u16)
    const size_t need = (size_t)BUF * 2 + 2ULL * 3 * DH * DH * 2
                      + (size_t)NC * COLS * 4;       // 216,006,656 B
    if (ws_size < need) return;

    u16*   buf   = (u16*)d_ws;
    u16*   Bp    = buf + BUF;
    u16*   Cp    = Bp + 3L * DH * DH;
    float* carry = (float*)(Cp + 3L * DH * DH);

    prep_k<<<(3 * DH * DH) / 256, 256, 0, stream>>>(B, C, Bp, Cp);

    // layer 0 GEMM1 (h0 fused)
    gemm_first<<<MT / 64, 512, 0, stream>>>(x, W0, b0, Bp, buf);
    scanA_k<<<(NC * COLS / 4) / 256, 256, 0, stream>>>(buf, a, 0, carry);
    scanC_k<<<(NC * COLS / 4) / 256, 256, 0, stream>>>(buf, a, 0, carry);

    // boundary l0->l1: xb_1 = relu(hs_0 @ C0) @ B1
    gemm_dual<<<MT / 64, 512, 0, stream>>>(buf, Cp, Bp + (long)DH * DH, buf);
    scanA_k<<<(NC * COLS / 4) / 256, 256, 0, stream>>>(buf, a, 1, carry);
    scanC_k<<<(NC * COLS / 4) / 256, 256, 0, stream>>>(buf, a, 1, carry);

    // boundary l1->l2: xb_2 = relu(hs_1 @ C1) @ B2
    gemm_dual<<<MT / 64, 512, 0, stream>>>(buf, Cp + (long)DH * DH,
                                           Bp + 2L * DH * DH, buf);
    scanA_k<<<(NC * COLS / 4) / 256, 256, 0, stream>>>(buf, a, 2, carry);
    scanC_k<<<(NC * COLS / 4) / 256, 256, 0, stream>>>(buf, a, 2, carry);

    // layer 2 GEMM2 with fused final reduction + residual
    gemm_last<<<MT / 64, 512, 0, stream>>>(buf, Cp + 2L * DH * DH,
                                           Wf, bf_, x, out);
}

// Round 15
// 874.968 us; speedup vs baseline: 1.6772x; 1.6772x over previous
//
#include <hip/hip_runtime.h>
#include <hip/hip_bf16.h>

// Problem constants (fixed by reference)
#define SEQ 784
#define BS  256
#define DH  512
#define MT  (SEQ * BS)   // 200704 rows
#define NL  3
#define NC  14           // scan chunks
#define CL  56           // chunk length (NC*CL == SEQ)
#define COLS (BS * DH)   // 131072 = 2^17

typedef unsigned short u16;
typedef __bf16  bf16x8  __attribute__((ext_vector_type(8)));
typedef float   f32x4   __attribute__((ext_vector_type(4)));
typedef unsigned short u16x8 __attribute__((ext_vector_type(8)));
typedef unsigned short u16x4 __attribute__((ext_vector_type(4)));
// (not ushortN: HIP's amd_hip_vector_types.h owns those names — R8 failure)

__device__ __forceinline__ u16 f2b(float f) {
    unsigned int x = __float_as_uint(f);
    unsigned int r = (x + 0x7FFFu + ((x >> 16) & 1u)) >> 16;   // RNE
    return (u16)r;
}
__device__ __forceinline__ float b2f(u16 u) {
    return __uint_as_float(((unsigned int)u) << 16);
}

// ---------------------------------------------------------------------------
// prep: pack B[l],C[l] (f32 (l,k,n)) -> bf16 MFMA-fragment order:
//   n = wd*64 + ni*16 + (lane&15);  k = g*32 + (lane>>4)*8 + e
// ---------------------------------------------------------------------------
__global__ __launch_bounds__(256) void prep_k(const float* __restrict__ B,
                                              const float* __restrict__ C,
                                              u16* __restrict__ Bp,
                                              u16* __restrict__ Cp)
{
    const long t = (long)blockIdx.x * 256 + threadIdx.x;   // 0 .. 3*2^18-1
    const int  e  = (int)(t & 7);
    const int  l  = (int)((t >> 3) & 63);
    const int  ni = (int)((t >> 9) & 3);
    const int  wd = (int)((t >> 11) & 7);
    const int  g  = (int)((t >> 14) & 15);
    const long lay = t >> 18;
    const int  n = wd * 64 + ni * 16 + (l & 15);
    const int  k = g * 32 + (l >> 4) * 8 + e;
    const long src = (lay << 18) + (long)k * DH + n;
    Bp[t] = f2b(B[src]);
    Cp[t] = f2b(C[src]);
}

// ===========================================================================
// GEMM family — measured-best core (R7/R12: ~120us, m97-ceiling-bound):
// 64x512 tile, 512 threads = 8 waves (wid = 64-col N-block),
// mfma_f32_16x16x32_bf16; W fragment-packed from L2 (coalesced dwordx4);
// A 64x64 sub-tile double-buffered in LDS, source-side XOR swizzle
// (conflict-free). Plain __syncthreads only.
//
// gemm_dual: fuses boundary GEMM2(l)+GEMM1(l+1); Y = relu(hs@C) lives only
// in LDS (A-staging swizzle format). R13/R14 spilled ~480B/thread: theory =
// scheduler HOISTS K-loop-2's 64 argument-only-dependent bv loads above the
// Y-write barrier into the region where acc is live (256 VGPRs of prefetch).
// R15 FIX: sched_barrier(0) fence after the Y-write sync + #pragma unroll 1
// on K-loop-2 (runtime t -> loop-carried bv addresses, prefetch bounded to
// one step, the proven gemm_ip pressure profile).
// ===========================================================================

#define GEMM_STEP_KK(ATILE, tt, ACC, WP)                                         \
    _Pragma("unroll")                                                            \
    for (int kk = 0; kk < 2; ++kk) {                                             \
        bf16x8 bv[4];                                                            \
        _Pragma("unroll")                                                        \
        for (int ni = 0; ni < 4; ++ni)                                           \
            bv[ni] = *(const bf16x8*)&(WP)[((long)((2 * (tt) + kk) * 32 +        \
                                                   wid * 4 + ni) << 9) +         \
                                           (lane << 3)];                         \
        const int fcol = ((kk * 4 + (lane >> 4)) ^ (lane & 7)) * 8;              \
        bf16x8 af[4];                                                            \
        _Pragma("unroll")                                                        \
        for (int i = 0; i < 4; ++i)                                              \
            af[i] = *(const bf16x8*)&(ATILE)[(i * 16 + (lane & 15)) * 64 + fcol];\
        _Pragma("unroll")                                                        \
        for (int mi = 0; mi < 4; ++mi)                                           \
            _Pragma("unroll")                                                    \
            for (int ni = 0; ni < 4; ++ni)                                       \
                (ACC)[mi][ni] = __builtin_amdgcn_mfma_f32_16x16x32_bf16(         \
                    af[mi], bv[ni], (ACC)[mi][ni], 0, 0, 0);                     \
    }

// Staged K-loop (prologue stage + per-step dbuf stage + __syncthreads)
#define GEMM_STAGED_KLOOP(ACC, WP)                                              \
    __builtin_amdgcn_global_load_lds(                                           \
        (const __attribute__((address_space(1))) void*)gax,                     \
        (__attribute__((address_space(3))) void*)                               \
            ((__attribute__((address_space(3))) char*)lds + tid * 16),          \
        16, 0, 0);                                                              \
    for (int t = 0; t < 8; ++t) {                                               \
        __syncthreads();                                                        \
        if (t < 7) {                                                            \
            __builtin_amdgcn_global_load_lds(                                   \
                (const __attribute__((address_space(1))) void*)(gax + (t + 1) * 64), \
                (__attribute__((address_space(3))) void*)                       \
                    ((__attribute__((address_space(3))) char*)lds +             \
                     ((t + 1) & 1) * 8192 + tid * 16),                          \
                16, 0, 0);                                                      \
        }                                                                       \
        const u16* Atile = lds + (t & 1) * 4096;                                \
        GEMM_STEP_KK(Atile, t, ACC, WP)                                         \
    }                                                                           \
    __syncthreads();

// Standard C-tile epilogue (LDS-staged coalesced stores, row-group swizzle)
#define GEMM_C_EPILOGUE(CT, ACC, RELU_FLAG, DST)                                \
    {                                                                           \
        const int rbase = (lane >> 4) * 4;                                      \
        const int cloc  = wid * 64 + (lane & 15);                               \
        _Pragma("unroll")                                                       \
        for (int mi = 0; mi < 4; ++mi)                                          \
            _Pragma("unroll")                                                   \
            for (int ni = 0; ni < 4; ++ni)                                      \
                _Pragma("unroll")                                               \
                for (int r = 0; r < 4; ++r) {                                   \
                    float v = (ACC)[mi][ni][r];                                 \
                    if (RELU_FLAG) v = fmaxf(v, 0.f);                           \
                    const int row = mi * 16 + rbase + r;                        \
                    const int col = (cloc + ni * 16) ^ (((row >> 2) & 3) * 16); \
                    (CT)[row * 512 + col] = f2b(v);                             \
                }                                                               \
        __syncthreads();                                                        \
        _Pragma("unroll")                                                       \
        for (int p = 0; p < 8; ++p) {                                           \
            const int e   = p * 4096 + tid * 8;                                 \
            const int row = e >> 9;                                             \
            const int col = e & 511;                                            \
            const int csw = col ^ (((row >> 2) & 3) * 16);                      \
            *(u16x8*)&(DST)[(bm + row) * DH + col] =                            \
                *(const u16x8*)&(CT)[row * 512 + csw];                          \
        }                                                                       \
    }

// ---- layer-0 GEMM1 with fused h0: A panel COMPUTED in-LDS from x,W0,b0 ----
__global__ __launch_bounds__(512, 4) void gemm_first(const float* __restrict__ x,
                                                     const float* __restrict__ W0,
                                                     const float* __restrict__ b0,
                                                     const u16* __restrict__ Wp,
                                                     u16* __restrict__ Y)
{
    __shared__ __align__(16) u16 lds[64 * 512];   // full A panel, aliased C tile

    const int tid  = threadIdx.x;
    const int lane = tid & 63;
    const int wid  = tid >> 6;
    const long bm  = (long)blockIdx.x * 64;

    const int prow = tid >> 3;
    const int slot = tid & 7;
    const float xv = x[bm + prow];

#pragma unroll
    for (int t = 0; t < 8; ++t) {
        const int k0 = t * 64 + ((slot ^ (prow & 7)) * 8);
        u16x8 o;
#pragma unroll
        for (int e = 0; e < 8; ++e)
            o[e] = f2b(fmaxf(fmaf(xv, W0[k0 + e], b0[k0 + e]), 0.f));
        *(u16x8*)&lds[t * 4096 + tid * 8] = o;
    }

    f32x4 acc[4][4];
#pragma unroll
    for (int i = 0; i < 4; ++i)
#pragma unroll
        for (int j = 0; j < 4; ++j)
            acc[i][j] = (f32x4){0.f, 0.f, 0.f, 0.f};

    __syncthreads();

#pragma unroll
    for (int t = 0; t < 8; ++t) {
        const u16* Atile = lds + t * 4096;
        GEMM_STEP_KK(Atile, t, acc, Wp)
    }
    __syncthreads();

    u16* Ctile = lds;
    GEMM_C_EPILOGUE(Ctile, acc, 0, Y)
}

// ---- fused boundary: xb_{l+1} = relu(hs @ C_l) @ B_{l+1} -------------------
// K-loop-1 (staged from buf) -> Y into LDS in A-staging swizzle format
// -> sched fence -> K-loop-2 (unroll 1, A from LDS) -> epilogue to buf.
// LDS: A-dbuf 16KB @0 + Y 64KB = 80KB -> 2 blocks/CU.
__global__ __launch_bounds__(512, 4) void gemm_dual(const u16* __restrict__ X,
                                                    const u16* __restrict__ WpC,
                                                    const u16* __restrict__ WpB,
                                                    u16* __restrict__ Yout)
{
    __shared__ __align__(16) u16 lds[8192 + 8 * 4096];   // 80 KB

    const int tid  = threadIdx.x;
    const int lane = tid & 63;
    const int wid  = tid >> 6;
    const long bm  = (long)blockIdx.x * 64;

    const int srow = tid >> 3;
    const int scol = (((tid & 7) ^ (srow & 7)) * 8);
    const u16* gax = X + (bm + srow) * DH + scol;

    f32x4 acc[4][4];
#pragma unroll
    for (int i = 0; i < 4; ++i)
#pragma unroll
        for (int j = 0; j < 4; ++j)
            acc[i][j] = (f32x4){0.f, 0.f, 0.f, 0.f};

    // ---- K-loop 1: T = hs @ C  (staged A from global) ----
    GEMM_STAGED_KLOOP(acc, WpC)

    // ---- write Y = relu(T) into LDS, A-staging swizzle format ----
    // logical (row, col): t = col>>6 == wid (each wave owns its own tile),
    // chunk = (col&63)>>3, e = col&7; dest chunk is XOR'd with row&7.
    u16* Yr = lds + 8192;
    {
        const int rbase = (lane >> 4) * 4;
#pragma unroll
        for (int mi = 0; mi < 4; ++mi)
#pragma unroll
            for (int ni = 0; ni < 4; ++ni) {
                const int chunk = ni * 2 + ((lane & 15) >> 3);
#pragma unroll
                for (int r = 0; r < 4; ++r) {
                    const int row = mi * 16 + rbase + r;
                    Yr[wid * 4096 + row * 64 + ((chunk ^ (row & 7)) * 8) + (lane & 7)]
                        = f2b(fmaxf(acc[mi][ni][r], 0.f));
                }
            }
    }
    __syncthreads();
    // R15 FIX: hard scheduling fence — forbid K-loop-2's bv loads (which
    // depend only on kernel args) from hoisting above this point into the
    // region where acc was live. R13/R14's ~480B/thread spill mechanism.
    __builtin_amdgcn_sched_barrier(0);

    // ---- K-loop 2: xb = Y @ B — reuse acc; unroll 1 bounds prefetch ----
#pragma unroll
    for (int i = 0; i < 4; ++i)
#pragma unroll
        for (int j = 0; j < 4; ++j)
            acc[i][j] = (f32x4){0.f, 0.f, 0.f, 0.f};

#pragma unroll 1
    for (int t = 0; t < 8; ++t) {
        const u16* Atile = Yr + t * 4096;
        GEMM_STEP_KK(Atile, t, acc, WpB)
    }
    __syncthreads();   // done reading Y; reuse Yr as C tile

    u16* Ctile = Yr;
    GEMM_C_EPILOGUE(Ctile, acc, 0, Yout)
}

// ---- layer-2 GEMM2 with fused final: out = relu(X@C)@Wf + bf + x ----------
__global__ __launch_bounds__(512, 4) void gemm_last(const u16* __restrict__ X,
                                                    const u16* __restrict__ Wp,
                                                    const float* __restrict__ Wf,
                                                    const float* __restrict__ bf_,
                                                    const float* __restrict__ x,
                                                    float* __restrict__ out)
{
    __shared__ __align__(16) u16 lds[64 * 512];
    float* partials = (float*)lds;             // [8][64] f32, used after K-loop

    const int tid  = threadIdx.x;
    const int lane = tid & 63;
    const int wid  = tid >> 6;
    const long bm  = (long)blockIdx.x * 64;

    const int srow = tid >> 3;
    const int scol = (((tid & 7) ^ (srow & 7)) * 8);
    const u16* gax = X + (bm + srow) * DH + scol;

    f32x4 acc[4][4];
#pragma unroll
    for (int i = 0; i < 4; ++i)
#pragma unroll
        for (int j = 0; j < 4; ++j)
            acc[i][j] = (f32x4){0.f, 0.f, 0.f, 0.f};

    GEMM_STAGED_KLOOP(acc, Wp)   // ends with __syncthreads(); lds -> partials

    const int cbase = wid * 64 + (lane & 15);
    float wf[4];
#pragma unroll
    for (int ni = 0; ni < 4; ++ni) wf[ni] = Wf[cbase + ni * 16];

    float part[4][4];
#pragma unroll
    for (int mi = 0; mi < 4; ++mi)
#pragma unroll
        for (int r = 0; r < 4; ++r) {
            float s = 0.f;
#pragma unroll
            for (int ni = 0; ni < 4; ++ni)
                s = fmaf(fmaxf(acc[mi][ni][r], 0.f), wf[ni], s);
            part[mi][r] = s;
        }
#pragma unroll
    for (int mi = 0; mi < 4; ++mi)
#pragma unroll
        for (int r = 0; r < 4; ++r) {
#pragma unroll
            for (int off = 1; off < 16; off <<= 1)
                part[mi][r] += __shfl_xor(part[mi][r], off, 64);
        }
    if ((lane & 15) == 0) {
        const int q = lane >> 4;
#pragma unroll
        for (int mi = 0; mi < 4; ++mi)
#pragma unroll
            for (int r = 0; r < 4; ++r)
                partials[wid * 64 + mi * 16 + q * 4 + r] = part[mi][r];
    }
    __syncthreads();
    if (tid < 64) {
        float s = 0.f;
#pragma unroll
        for (int w = 0; w < 8; ++w) s += partials[w * 64 + tid];
        out[bm + tid] = s + bf_[0] + x[bm + tid];
    }
}

// ---------------------------------------------------------------------------
// Chunked parallel scan, 2 phases (scanB fused into scanC's prologue —
// verified absmax-identical). u16x4 vectorized (4 cols/thread).
// ---------------------------------------------------------------------------
__global__ __launch_bounds__(256) void scanA_k(const u16* __restrict__ buf,
                                               const float* __restrict__ a_all,
                                               int layer,
                                               float* __restrict__ carry)
{
    const long T   = (long)blockIdx.x * 256 + threadIdx.x;  // 0 .. NC*COLS/4-1
    const int col4 = (int)(T & (COLS / 4 - 1)) * 4;
    const int c    = (int)(T >> 15);
    const f32x4 av = *(const f32x4*)&a_all[layer * DH + (col4 & (DH - 1))];
    const u16* p = buf + (long)c * CL * COLS + col4;

    float h[4] = {0.f, 0.f, 0.f, 0.f};
    u16x4 pre[8];
#pragma unroll
    for (int i = 0; i < 8; ++i) pre[i] = *(const u16x4*)&p[(long)i * COLS];
    for (int s8 = 0; s8 < CL; s8 += 8) {
        const bool more = (s8 + 8) < CL;
#pragma unroll
        for (int j = 0; j < 8; ++j) {
            const u16x4 v = pre[j];
            if (more) pre[j] = *(const u16x4*)&p[(long)(s8 + 8 + j) * COLS];
#pragma unroll
            for (int i = 0; i < 4; ++i)
                h[i] = fmaf(h[i], av[i], b2f((u16)v[i]));
        }
    }
    *(f32x4*)&carry[(long)c * COLS + col4] = (f32x4){h[0], h[1], h[2], h[3]};
}

// Phase C (+fused B): carry-in = prefix of raw carries (c uniform per block;
// identical fp recurrence to the old scanB); then scan CL steps, write bf16.
__global__ __launch_bounds__(256) void scanC_k(u16* __restrict__ buf,
                                               const float* __restrict__ a_all,
                                               int layer,
                                               const float* __restrict__ carry)
{
    const long T   = (long)blockIdx.x * 256 + threadIdx.x;
    const int col4 = (int)(T & (COLS / 4 - 1)) * 4;
    const int c    = (int)(T >> 15);
    const f32x4 av = *(const f32x4*)&a_all[layer * DH + (col4 & (DH - 1))];
    u16* p = buf + (long)c * CL * COLS + col4;

    float h[4];
#pragma unroll
    for (int i = 0; i < 4; ++i) h[i] = 0.f;
    {
        float pw[4];
#pragma unroll
        for (int i = 0; i < 4; ++i) {
            float a2 = av[i] * av[i], a4 = a2 * a2, a8 = a4 * a4;
            float a16 = a8 * a8, a32 = a16 * a16;
            pw[i] = a32 * a16 * a8;            // a^56
        }
        for (int cc = 0; cc < c; ++cc) {       // c uniform within block
            const f32x4 cr = *(const f32x4*)&carry[(long)cc * COLS + col4];
#pragma unroll
            for (int i = 0; i < 4; ++i)
                h[i] = fmaf(h[i], pw[i], cr[i]);
        }
    }

    u16x4 pre[8];
#pragma unroll
    for (int i = 0; i < 8; ++i) pre[i] = *(const u16x4*)&p[(long)i * COLS];
    for (int s8 = 0; s8 < CL; s8 += 8) {
        const bool more = (s8 + 8) < CL;
#pragma unroll
        for (int j = 0; j < 8; ++j) {
            const u16x4 v = pre[j];
            if (more) pre[j] = *(const u16x4*)&p[(long)(s8 + 8 + j) * COLS];
            u16x4 o;
#pragma unroll
            for (int i = 0; i < 4; ++i) {
                h[i] = fmaf(h[i], av[i], b2f((u16)v[i]));
                o[i] = f2b(h[i]);
            }
            *(u16x4*)&p[(long)(s8 + j) * COLS] = o;
        }
    }
}

// ---------------------------------------------------------------------------
extern "C" void kernel_launch(void* const* d_in, const int* in_sizes, int n_in,
                              void* d_out, int out_size, void* d_ws, size_t ws_size,
                              hipStream_t stream)
{
    const float* x   = (const float*)d_in[0];
    const float* W0  = (const float*)d_in[1];
    const float* b0  = (const float*)d_in[2];
    const float* a   = (const float*)d_in[3];
    const float* B   = (const float*)d_in[4];
    const float* C   = (const float*)d_in[5];
    const float* Wf  = (const float*)d_in[6];
    const float* bf_ = (const float*)d_in[7];
    float* out = (float*)d_out;

    const long BUF = (long)MT * DH;                  // 102,760,448 elements (u16)
    const size_t need = (size_t)BUF * 2 + 2ULL * 3 * DH * DH * 2
                      + (size_t)NC * COLS * 4;       // 216,006,656 B
    if (ws_size < need) return;

    u16*   buf   = (u16*)d_ws;
    u16*   Bp    = buf + BUF;
    u16*   Cp    = Bp + 3L * DH * DH;
    float* carry = (float*)(Cp + 3L * DH * DH);

    prep_k<<<(3 * DH * DH) / 256, 256, 0, stream>>>(B, C, Bp, Cp);

    // layer 0 GEMM1 (h0 fused)
    gemm_first<<<MT / 64, 512, 0, stream>>>(x, W0, b0, Bp, buf);
    scanA_k<<<(NC * COLS / 4) / 256, 256, 0, stream>>>(buf, a, 0, carry);
    scanC_k<<<(NC * COLS / 4) / 256, 256, 0, stream>>>(buf, a, 0, carry);

    // boundary l0->l1: xb_1 = relu(hs_0 @ C0) @ B1
    gemm_dual<<<MT / 64, 512, 0, stream>>>(buf, Cp, Bp + (long)DH * DH, buf);
    scanA_k<<<(NC * COLS / 4) / 256, 256, 0, stream>>>(buf, a, 1, carry);
    scanC_k<<<(NC * COLS / 4) / 256, 256, 0, stream>>>(buf, a, 1, carry);

    // boundary l1->l2: xb_2 = relu(hs_1 @ C1) @ B2
    gemm_dual<<<MT / 64, 512, 0, stream>>>(buf, Cp + (long)DH * DH,
                                           Bp + 2L * DH * DH, buf);
    scanA_k<<<(NC * COLS / 4) / 256, 256, 0, stream>>>(buf, a, 2, carry);
    scanC_k<<<(NC * COLS / 4) / 256, 256, 0, stream>>>(buf, a, 2, carry);

    // layer 2 GEMM2 with fused final reduction + residual
    gemm_last<<<MT / 64, 512, 0, stream>>>(buf, Cp + 2L * DH * DH,
                                           Wf, bf_, x, out);
}